// Round 1
// 888.698 us; speedup vs baseline: 1.3615x; 1.3615x over previous
//
#include <hip/hip_runtime.h>
#include <math.h>

// Problem constants
#define BB 8
#define TT 512
#define EE 64
#define HH 512
#define VV 32000
#define MM 4096      // B*T
#define G3 1536      // 3*H

typedef _Float16 half8 __attribute__((ext_vector_type(8)));
typedef float floatx4 __attribute__((ext_vector_type(4)));

// ---------------------------------------------------------------------------
// async global->LDS 16B copy (wave-uniform LDS base + lane*16 scatter)
__device__ __forceinline__ void gld_lds16(const _Float16* g, _Float16* l) {
    __builtin_amdgcn_global_load_lds(
        (const __attribute__((address_space(1))) void*)(const void*)g,
        (__attribute__((address_space(3))) void*)(void*)l, 16, 0, 0);
}

// ---------------------------------------------------------------------------
// W [K][N] fp32  ->  Wt [N][K] fp16   (LDS-tiled transpose, 32x32 tiles)
__global__ __launch_bounds__(256) void transpose_f32_f16(
    const float* __restrict__ W, _Float16* __restrict__ Wt, int K, int N)
{
    __shared__ float tile[32][33];
    const int n0 = blockIdx.x * 32;
    const int k0 = blockIdx.y * 32;
    const int tx = threadIdx.x, ty = threadIdx.y;   // 32 x 8
    #pragma unroll
    for (int i = 0; i < 32; i += 8)
        tile[ty + i][tx] = W[(k0 + ty + i) * N + n0 + tx];
    __syncthreads();
    #pragma unroll
    for (int i = 0; i < 32; i += 8)
        Wt[(n0 + ty + i) * K + k0 + tx] = (_Float16)tile[tx][ty + i];
}

// ---------------------------------------------------------------------------
// x[(t*B+b)*E + e] = emb[ids[b*T + t]*E + e]  (fp16, t-major rows for layer 1)
__global__ __launch_bounds__(256) void gather_embed(
    const int* __restrict__ ids, const float* __restrict__ emb,
    _Float16* __restrict__ x)
{
    const int tid = blockIdx.x * 256 + threadIdx.x;   // M*E threads
    const int m = tid >> 6, e = tid & 63;
    const int t = m >> 3, b = m & 7;
    const int id = ids[b * TT + t];
    x[tid] = (_Float16)emb[id * EE + e];
}

// ---------------------------------------------------------------------------
// MFMA fp16 GEMM:  C[M][N] = A[M][K] * Bt[N][K]^T + bias[N]   (fp32 out)
// 128x128 tile, BK=64, 256 thr = 2x2 waves of 64x64, XOR-swizzled LDS.
// act==1: apply QRNN activations in epilogue (n<H -> tanh, else sigmoid).
// Block->tile map: bijective XCD swizzle (nwg%8==0 for all launches here),
// m-fastest within each XCD chunk so an XCD's ~31 consecutive N-panels
// (~4MB of Bt) stay L2-resident across all 32 M-blocks.
__global__ __launch_bounds__(256) void gemm_f16(
    const _Float16* __restrict__ A, const _Float16* __restrict__ Bt,
    const float* __restrict__ bias, float* __restrict__ C,
    int Ndim, int Kdim, int act)
{
    __shared__ _Float16 As[128 * 64];   // [row][granule^ (row&7)] granule=8 f16
    __shared__ _Float16 Bs[128 * 64];

    const int nb  = gridDim.x, mbl = gridDim.y;
    const int bid = blockIdx.y * nb + blockIdx.x;
    const int sw  = (bid & 7) * ((nb * mbl) >> 3) + (bid >> 3);
    const int n0 = (sw / mbl) * 128;
    const int m0 = (sw % mbl) * 128;
    const int tid = threadIdx.x;
    const int wid = tid >> 6;
    const int lane = tid & 63;
    const int wm = wid & 1, wn = wid >> 1;
    const int quad = lane >> 4, rlo = lane & 15;

    floatx4 acc[4][4] = {};

    for (int k0 = 0; k0 < Kdim; k0 += 64) {
        __syncthreads();   // previous compute done before LDS overwrite
        #pragma unroll
        for (int i = 0; i < 4; ++i) {
            const int sbase = wid * 256 + i * 64;       // wave-uniform granule base
            const int slot = sbase + lane;              // this lane's granule
            const int r = slot >> 3;                    // tile row 0..127
            const int p = slot & 7;                     // stored granule position
            const int srcg = p ^ (r & 7);               // XOR swizzle source
            gld_lds16(A  + (m0 + r) * Kdim + k0 + srcg * 8, As + sbase * 8);
            gld_lds16(Bt + (n0 + r) * Kdim + k0 + srcg * 8, Bs + sbase * 8);
        }
        __syncthreads();   // compiler emits s_waitcnt vmcnt(0) before s_barrier

        #pragma unroll
        for (int kk = 0; kk < 64; kk += 32) {
            const int gi = (kk >> 3) + quad;            // wanted granule index
            half8 af[4], bf[4];
            #pragma unroll
            for (int mi = 0; mi < 4; ++mi) {
                const int ra = wm * 64 + mi * 16 + rlo;
                af[mi] = *(const half8*)(As + (ra * 8 + (gi ^ (ra & 7))) * 8);
            }
            #pragma unroll
            for (int ni = 0; ni < 4; ++ni) {
                const int rb = wn * 64 + ni * 16 + rlo;
                bf[ni] = *(const half8*)(Bs + (rb * 8 + (gi ^ (rb & 7))) * 8);
            }
            #pragma unroll
            for (int mi = 0; mi < 4; ++mi)
                #pragma unroll
                for (int ni = 0; ni < 4; ++ni)
                    acc[mi][ni] = __builtin_amdgcn_mfma_f32_16x16x32_f16(
                        af[mi], bf[ni], acc[mi][ni], 0, 0, 0);
        }
    }

    // Epilogue. C/D mapping: col = lane&15, row = quad*4 + reg  (verified m89/m91)
    #pragma unroll
    for (int ni = 0; ni < 4; ++ni) {
        const int gn = n0 + wn * 64 + ni * 16 + rlo;
        const float bv = bias[gn];
        #pragma unroll
        for (int mi = 0; mi < 4; ++mi) {
            const int gm = m0 + wm * 64 + mi * 16 + quad * 4;
            #pragma unroll
            for (int r = 0; r < 4; ++r) {
                float v = acc[mi][ni][r] + bv;
                if (act)
                    v = (gn < HH) ? tanhf(v) : 1.f / (1.f + expf(-v));
                C[(gm + r) * Ndim + gn] = v;
            }
        }
    }
}

// ---------------------------------------------------------------------------
// QRNN fo-pool, chunked parallel scan over T.
// g holds ACTIVATED z,f,o (fp32): g[(t*B+b)*3H + {h, H+h, 2H+h}].
// Recurrence c_t = f_t*c_{t-1} + (1-f_t)*z_t is linear: a chunk [t0,t1) maps
// c_in -> A*c_in + B with A = prod f, B = chunk-local scan from 0.
// Phase A: each thread scans its 32-step chunk (A,B) -> LDS.
// Phase B: per-thread combine of preceding chunks (<=15 LDS FMAs).
// Phase C: rescan with correct carry, write h = o*c (fp16).
// Layout: block = 16 channels x 16 chunks = 256 thr; grid = 4096/16 = 256.
//   layer1: base_mult=H,   t_stride=B*H  -> t-major rows (feeds GEMM2)
//   layer2: base_mult=T*H, t_stride=H    -> b-major rows (feeds projection)
#define NCHUNK 16
#define CHPB 16                 // channels per block
#define CHL (TT / NCHUNK)       // 32 steps per chunk

__global__ __launch_bounds__(256) void fo_pool_scan(
    const float* __restrict__ g, _Float16* __restrict__ hout,
    int base_mult, int t_stride)
{
    __shared__ float sA[NCHUNK][CHPB];
    __shared__ float sB[NCHUNK][CHPB];
    const int c_idx = threadIdx.x & (CHPB - 1);
    const int chunk = threadIdx.x >> 4;
    const int ch = blockIdx.x * CHPB + c_idx;        // channel 0..4095
    const int b = ch >> 9, h = ch & 511;
    const int t0 = chunk * CHL;
    const float* gp = g + (size_t)(t0 * BB + b) * G3 + h;

    // phase A: local scan with c0=0, accumulate A = prod f
    float c = 0.f, Aa = 1.f;
    {
        const float* p = gp;
        #pragma unroll 8
        for (int t = 0; t < CHL; ++t) {
            const float z = p[0];
            const float f = p[HH];
            c = f * c + (1.f - f) * z;
            Aa *= f;
            p += BB * G3;
        }
    }
    sA[chunk][c_idx] = Aa;
    sB[chunk][c_idx] = c;
    __syncthreads();

    // phase B: carry into this chunk = fold of chunks 0..chunk-1 in order
    float carry = 0.f;
    #pragma unroll
    for (int j = 0; j < NCHUNK - 1; ++j)
        if (j < chunk) carry = sA[j][c_idx] * carry + sB[j][c_idx];

    // phase C: rescan with correct carry, write outputs
    c = carry;
    int oidx = b * base_mult + h + t0 * t_stride;
    const float* p = gp;
    #pragma unroll 8
    for (int t = 0; t < CHL; ++t) {
        const float z = p[0];
        const float f = p[HH];
        const float o = p[2 * HH];
        c = f * c + (1.f - f) * z;
        hout[oidx] = (_Float16)(o * c);
        p += BB * G3;
        oidx += t_stride;
    }
}

// ---------------------------------------------------------------------------
extern "C" void kernel_launch(void* const* d_in, const int* in_sizes, int n_in,
                              void* d_out, int out_size, void* d_ws, size_t ws_size,
                              hipStream_t stream) {
    (void)in_sizes; (void)n_in; (void)out_size; (void)ws_size;
    const int*   ids = (const int*)d_in[0];
    const float* emb = (const float*)d_in[1];
    const float* W1  = (const float*)d_in[2];
    const float* b1  = (const float*)d_in[3];
    const float* W2  = (const float*)d_in[4];
    const float* b2  = (const float*)d_in[5];
    const float* Wp  = (const float*)d_in[6];
    const float* bp  = (const float*)d_in[7];
    float* out = (float*)d_out;

    // workspace layout (256B-aligned offsets), ~68.6 MB total
    char* ws = (char*)d_ws;
    _Float16* x_h  = (_Float16*)(ws);                 // 4096*64   fp16
    _Float16* W1t  = (_Float16*)(ws + 524288);        // 1536*64   fp16 [N][K]
    _Float16* W2t  = (_Float16*)(ws + 720896);        // 1536*512  fp16 [N][K]
    _Float16* Wpt  = (_Float16*)(ws + 2293760);       // 32000*512 fp16 [N][K]
    float*    gbuf = (float*)   (ws + 35061760);      // 4096*1536 fp32 (reused)
    _Float16* h1   = (_Float16*)(ws + 60227584);      // 4096*512  fp16
    _Float16* h2   = (_Float16*)(ws + 64421888);      // 4096*512  fp16

    transpose_f32_f16<<<dim3(G3 / 32, EE / 32), dim3(32, 8), 0, stream>>>(W1, W1t, EE, G3);
    transpose_f32_f16<<<dim3(G3 / 32, HH / 32), dim3(32, 8), 0, stream>>>(W2, W2t, HH, G3);
    transpose_f32_f16<<<dim3(VV / 32, HH / 32), dim3(32, 8), 0, stream>>>(Wp, Wpt, HH, VV);
    gather_embed<<<MM * EE / 256, 256, 0, stream>>>(ids, emb, x_h);

    // GEMMs with fused QRNN activations (act=1) for the two recurrent layers
    gemm_f16<<<dim3(G3 / 128, MM / 128), 256, 0, stream>>>(x_h, W1t, b1, gbuf, G3, EE, 1);
    fo_pool_scan<<<MM / CHPB, 256, 0, stream>>>(gbuf, h1, HH, BB * HH);
    gemm_f16<<<dim3(G3 / 128, MM / 128), 256, 0, stream>>>(h1, W2t, b2, gbuf, G3, HH, 1);
    fo_pool_scan<<<MM / CHPB, 256, 0, stream>>>(gbuf, h2, TT * HH, HH);
    gemm_f16<<<dim3(VV / 128, MM / 128), 256, 0, stream>>>(h2, Wpt, bp, out, VV, HH, 0);
}

// Round 2
// 875.096 us; speedup vs baseline: 1.3827x; 1.0155x over previous
//
#include <hip/hip_runtime.h>
#include <math.h>

// Problem constants
#define BB 8
#define TT 512
#define EE 64
#define HH 512
#define VV 32000
#define MM 4096      // B*T
#define G3 1536      // 3*H

typedef _Float16 half8 __attribute__((ext_vector_type(8)));
typedef float floatx4 __attribute__((ext_vector_type(4)));

// ---------------------------------------------------------------------------
// async global->LDS 16B copy (wave-uniform LDS base + lane*16 scatter)
__device__ __forceinline__ void gld_lds16(const _Float16* g, _Float16* l) {
    __builtin_amdgcn_global_load_lds(
        (const __attribute__((address_space(1))) void*)(const void*)g,
        (__attribute__((address_space(3))) void*)(void*)l, 16, 0, 0);
}

// ---------------------------------------------------------------------------
// W [K][N] fp32  ->  Wt [N][K] fp16   (LDS-tiled transpose, 32x32 tiles)
__global__ __launch_bounds__(256) void transpose_f32_f16(
    const float* __restrict__ W, _Float16* __restrict__ Wt, int K, int N)
{
    __shared__ float tile[32][33];
    const int n0 = blockIdx.x * 32;
    const int k0 = blockIdx.y * 32;
    const int tx = threadIdx.x, ty = threadIdx.y;   // 32 x 8
    #pragma unroll
    for (int i = 0; i < 32; i += 8)
        tile[ty + i][tx] = W[(k0 + ty + i) * N + n0 + tx];
    __syncthreads();
    #pragma unroll
    for (int i = 0; i < 32; i += 8)
        Wt[(n0 + ty + i) * K + k0 + tx] = (_Float16)tile[tx][ty + i];
}

// ---------------------------------------------------------------------------
// x[(t*B+b)*E + e] = emb[ids[b*T + t]*E + e]  (fp16, t-major rows for layer 1)
__global__ __launch_bounds__(256) void gather_embed(
    const int* __restrict__ ids, const float* __restrict__ emb,
    _Float16* __restrict__ x)
{
    const int tid = blockIdx.x * 256 + threadIdx.x;   // M*E threads
    const int m = tid >> 6, e = tid & 63;
    const int t = m >> 3, b = m & 7;
    const int id = ids[b * TT + t];
    x[tid] = (_Float16)emb[id * EE + e];
}

// ---------------------------------------------------------------------------
// MFMA fp16 GEMM:  C[M][N] = A[M][K] * Bt[N][K]^T + bias[N]   (fp32 out)
// 128x128 tile, BK=32, 2-phase double-buffered LDS (stage t+1 issued BEFORE
// compute t; single vmcnt(0)+s_barrier per K-tile -> prefetch latency hides
// under MFMA + other resident blocks).  LDS total 32 KB -> 5 blocks/CU.
//
// LDS layout: physical rows of 128 B hold TWO logical tile rows (BK=32 f16
// = 64 B each); granule slot sp = s ^ (pr&7), s = (r&1)*4 + g.  This keeps
// ds_read_b128 at 2-way bank aliasing (free, m136) -- a naive 64-B row
// layout would be 4-way.  Stage source pre-applies the same involution so
// global_load_lds's linear dest stays correct (guide rule 21).
//
// act==1: QRNN activations in epilogue (n<H -> tanh, else sigmoid), normal
// stores (gbuf is re-read by fo_pool from L3).
// act==0: nontemporal C stores -- the 524 MB logits stream must not evict
// Wpt (32.8 MB) from L3; round-1 profile showed 330 MB of HBM refetch.
__global__ __launch_bounds__(256) void gemm_f16(
    const _Float16* __restrict__ A, const _Float16* __restrict__ Bt,
    const float* __restrict__ bias, float* __restrict__ C,
    int Ndim, int Kdim, int act)
{
    __shared__ __align__(16) _Float16 As[2][4096];   // 2 x 8 KB
    __shared__ __align__(16) _Float16 Bs[2][4096];

    const int nb  = gridDim.x, mbl = gridDim.y;
    const int bid = blockIdx.y * nb + blockIdx.x;
    const int sw  = (bid & 7) * ((nb * mbl) >> 3) + (bid >> 3);
    const int n0 = (sw / mbl) * 128;
    const int m0 = (sw % mbl) * 128;
    const int tid = threadIdx.x;
    const int wid = tid >> 6;
    const int lane = tid & 63;
    const int wm = wid & 1, wn = wid >> 1;
    const int quad = lane >> 4, rlo = lane & 15;

    // staging decode (constant per thread): 2 granules per matrix per thread
    const _Float16* asrc[2];
    const _Float16* bsrc[2];
    int dstg[2];
    #pragma unroll
    for (int i = 0; i < 2; ++i) {
        const int slot = i * 256 + wid * 64 + lane;
        const int pr = slot >> 3, sp = slot & 7;      // phys row, stored slot
        const int s  = sp ^ (pr & 7);                 // source slot (involution)
        const int r  = pr * 2 + (s >> 2);             // logical tile row
        const int g  = s & 3;                         // K-granule (8 f16)
        asrc[i] = A  + (size_t)(m0 + r) * Kdim + g * 8;
        bsrc[i] = Bt + (size_t)(n0 + r) * Kdim + g * 8;
        dstg[i] = (i * 256 + wid * 64) * 8;           // wave-uniform f16 offset
    }

    floatx4 acc[4][4] = {};
    const int NT = Kdim >> 5;                         // BK = 32

    // prologue: stage K-tile 0 into buf 0
    #pragma unroll
    for (int i = 0; i < 2; ++i) {
        gld_lds16(asrc[i], &As[0][dstg[i]]);
        gld_lds16(bsrc[i], &Bs[0][dstg[i]]);
    }
    asm volatile("s_waitcnt vmcnt(0)\n\ts_barrier" ::: "memory");

    for (int t = 0; t < NT; ++t) {
        const int cur = t & 1;
        if (t + 1 < NT) {                             // issue next-tile prefetch
            const int k1 = (t + 1) << 5;
            #pragma unroll
            for (int i = 0; i < 2; ++i) {
                gld_lds16(asrc[i] + k1, &As[cur ^ 1][dstg[i]]);
                gld_lds16(bsrc[i] + k1, &Bs[cur ^ 1][dstg[i]]);
            }
        }

        half8 af[4], bf[4];
        #pragma unroll
        for (int mi = 0; mi < 4; ++mi) {
            const int ra = wm * 64 + mi * 16 + rlo;
            const int pr = ra >> 1;
            const int sp = (((ra & 1) << 2) | quad) ^ (pr & 7);
            af[mi] = *(const half8*)(&As[cur][(pr * 8 + sp) * 8]);
        }
        #pragma unroll
        for (int ni = 0; ni < 4; ++ni) {
            const int rb = wn * 64 + ni * 16 + rlo;
            const int pr = rb >> 1;
            const int sp = (((rb & 1) << 2) | quad) ^ (pr & 7);
            bf[ni] = *(const half8*)(&Bs[cur][(pr * 8 + sp) * 8]);
        }
        #pragma unroll
        for (int mi = 0; mi < 4; ++mi)
            #pragma unroll
            for (int ni = 0; ni < 4; ++ni)
                acc[mi][ni] = __builtin_amdgcn_mfma_f32_16x16x32_f16(
                    af[mi], bf[ni], acc[mi][ni], 0, 0, 0);

        // drain ONLY the prefetch issued above (one per tile), then barrier
        asm volatile("s_waitcnt vmcnt(0)\n\ts_barrier" ::: "memory");
    }

    // Epilogue. C/D mapping: col = lane&15, row = quad*4 + reg  (verified m89/m91)
    #pragma unroll
    for (int ni = 0; ni < 4; ++ni) {
        const int gn = n0 + wn * 64 + ni * 16 + rlo;
        const float bv = bias[gn];
        #pragma unroll
        for (int mi = 0; mi < 4; ++mi) {
            const int gm = m0 + wm * 64 + mi * 16 + quad * 4;
            #pragma unroll
            for (int r = 0; r < 4; ++r) {
                float v = acc[mi][ni][r] + bv;
                if (act) {
                    v = (gn < HH) ? tanhf(v) : 1.f / (1.f + expf(-v));
                    C[(size_t)(gm + r) * Ndim + gn] = v;
                } else {
                    __builtin_nontemporal_store(v, &C[(size_t)(gm + r) * Ndim + gn]);
                }
            }
        }
    }
}

// ---------------------------------------------------------------------------
// QRNN fo-pool, chunked parallel scan over T.
// g holds ACTIVATED z,f,o (fp32): g[(t*B+b)*3H + {h, H+h, 2H+h}].
#define NCHUNK 16
#define CHPB 16                 // channels per block
#define CHL (TT / NCHUNK)       // 32 steps per chunk

__global__ __launch_bounds__(256) void fo_pool_scan(
    const float* __restrict__ g, _Float16* __restrict__ hout,
    int base_mult, int t_stride)
{
    __shared__ float sA[NCHUNK][CHPB];
    __shared__ float sB[NCHUNK][CHPB];
    const int c_idx = threadIdx.x & (CHPB - 1);
    const int chunk = threadIdx.x >> 4;
    const int ch = blockIdx.x * CHPB + c_idx;        // channel 0..4095
    const int b = ch >> 9, h = ch & 511;
    const int t0 = chunk * CHL;
    const float* gp = g + (size_t)(t0 * BB + b) * G3 + h;

    // phase A: local scan with c0=0, accumulate A = prod f
    float c = 0.f, Aa = 1.f;
    {
        const float* p = gp;
        #pragma unroll 8
        for (int t = 0; t < CHL; ++t) {
            const float z = p[0];
            const float f = p[HH];
            c = f * c + (1.f - f) * z;
            Aa *= f;
            p += BB * G3;
        }
    }
    sA[chunk][c_idx] = Aa;
    sB[chunk][c_idx] = c;
    __syncthreads();

    // phase B: carry into this chunk = fold of chunks 0..chunk-1 in order
    float carry = 0.f;
    #pragma unroll
    for (int j = 0; j < NCHUNK - 1; ++j)
        if (j < chunk) carry = sA[j][c_idx] * carry + sB[j][c_idx];

    // phase C: rescan with correct carry, write outputs
    c = carry;
    int oidx = b * base_mult + h + t0 * t_stride;
    const float* p = gp;
    #pragma unroll 8
    for (int t = 0; t < CHL; ++t) {
        const float z = p[0];
        const float f = p[HH];
        const float o = p[2 * HH];
        c = f * c + (1.f - f) * z;
        hout[oidx] = (_Float16)(o * c);
        p += BB * G3;
        oidx += t_stride;
    }
}

// ---------------------------------------------------------------------------
extern "C" void kernel_launch(void* const* d_in, const int* in_sizes, int n_in,
                              void* d_out, int out_size, void* d_ws, size_t ws_size,
                              hipStream_t stream) {
    (void)in_sizes; (void)n_in; (void)out_size; (void)ws_size;
    const int*   ids = (const int*)d_in[0];
    const float* emb = (const float*)d_in[1];
    const float* W1  = (const float*)d_in[2];
    const float* b1  = (const float*)d_in[3];
    const float* W2  = (const float*)d_in[4];
    const float* b2  = (const float*)d_in[5];
    const float* Wp  = (const float*)d_in[6];
    const float* bp  = (const float*)d_in[7];
    float* out = (float*)d_out;

    // workspace layout (256B-aligned offsets), ~68.6 MB total
    char* ws = (char*)d_ws;
    _Float16* x_h  = (_Float16*)(ws);                 // 4096*64   fp16
    _Float16* W1t  = (_Float16*)(ws + 524288);        // 1536*64   fp16 [N][K]
    _Float16* W2t  = (_Float16*)(ws + 720896);        // 1536*512  fp16 [N][K]
    _Float16* Wpt  = (_Float16*)(ws + 2293760);       // 32000*512 fp16 [N][K]
    float*    gbuf = (float*)   (ws + 35061760);      // 4096*1536 fp32 (reused)
    _Float16* h1   = (_Float16*)(ws + 60227584);      // 4096*512  fp16
    _Float16* h2   = (_Float16*)(ws + 64421888);      // 4096*512  fp16

    transpose_f32_f16<<<dim3(G3 / 32, EE / 32), dim3(32, 8), 0, stream>>>(W1, W1t, EE, G3);
    transpose_f32_f16<<<dim3(G3 / 32, HH / 32), dim3(32, 8), 0, stream>>>(W2, W2t, HH, G3);
    transpose_f32_f16<<<dim3(VV / 32, HH / 32), dim3(32, 8), 0, stream>>>(Wp, Wpt, HH, VV);
    gather_embed<<<MM * EE / 256, 256, 0, stream>>>(ids, emb, x_h);

    // GEMMs with fused QRNN activations (act=1) for the two recurrent layers
    gemm_f16<<<dim3(G3 / 128, MM / 128), 256, 0, stream>>>(x_h, W1t, b1, gbuf, G3, EE, 1);
    fo_pool_scan<<<MM / CHPB, 256, 0, stream>>>(gbuf, h1, HH, BB * HH);
    gemm_f16<<<dim3(G3 / 128, MM / 128), 256, 0, stream>>>(h1, W2t, b2, gbuf, G3, HH, 1);
    fo_pool_scan<<<MM / CHPB, 256, 0, stream>>>(gbuf, h2, TT * HH, HH);
    gemm_f16<<<dim3(VV / 128, MM / 128), 256, 0, stream>>>(h2, Wpt, bp, out, VV, HH, 0);
}